// Round 14
// baseline (68.118 us; speedup 1.0000x reference)
//
#include <hip/hip_runtime.h>
#include <hip/hip_bf16.h>

#define B_SZ 1024
#define T_LEN 8192
#define NBINS 819            // T//10
#define PSD_LDA 1792         // padded bf16 row stride = 4 x 448 (zero-padded 1638..1791)
#define PI_F 3.14159265358979323846f

typedef __attribute__((ext_vector_type(8))) short bf16x8;
typedef __attribute__((ext_vector_type(4))) float f32x4;

// ---- tables ---------------------------------------------------------------
__device__ constexpr float W32C[32] = {   // cos(2*pi*m/32)
  1.0f, 0.980785280f, 0.923879533f, 0.831469612f, 0.707106781f, 0.555570233f,
  0.382683432f, 0.195090322f, 0.0f, -0.195090322f, -0.382683432f, -0.555570233f,
  -0.707106781f, -0.831469612f, -0.923879533f, -0.980785280f, -1.0f,
  -0.980785280f, -0.923879533f, -0.831469612f, -0.707106781f, -0.555570233f,
  -0.382683432f, -0.195090322f, 0.0f, 0.195090322f, 0.382683432f, 0.555570233f,
  0.707106781f, 0.831469612f, 0.923879533f, 0.980785280f};
__device__ constexpr float W32S[32] = {   // -sin(2*pi*m/32)
  0.0f, -0.195090322f, -0.382683432f, -0.555570233f, -0.707106781f,
  -0.831469612f, -0.923879533f, -0.980785280f, -1.0f, -0.980785280f,
  -0.923879533f, -0.831469612f, -0.707106781f, -0.555570233f, -0.382683432f,
  -0.195090322f, 0.0f, 0.195090322f, 0.382683432f, 0.555570233f, 0.707106781f,
  0.831469612f, 0.923879533f, 0.980785280f, 1.0f, 0.980785280f, 0.923879533f,
  0.831469612f, 0.707106781f, 0.555570233f, 0.382683432f, 0.195090322f};
__device__ constexpr float E8C[8] = {  // cos(pi*c/4)
  1.0f, 0.707106781f, 0.0f, -0.707106781f, -1.0f, -0.707106781f, 0.0f, 0.707106781f};
__device__ constexpr float E8S[8] = {  // sin(pi*c/4)
  0.0f, 0.707106781f, 1.0f, 0.707106781f, 0.0f, -0.707106781f, -1.0f, -0.707106781f};

__device__ __forceinline__ unsigned short bfb(float x) {
  __hip_bfloat16 h = __float2bfloat16(x);
  return *(unsigned short*)&h;
}
__device__ __forceinline__ float bff(unsigned short u) {
  union { unsigned u; float f; } v; v.u = ((unsigned)u) << 16; return v.f;
}
__device__ __forceinline__ unsigned cvtpk(float r, float i) {
  unsigned out;
  asm("v_cvt_pk_bf16_f32 %0, %1, %2" : "=v"(out) : "v"(r), "v"(i));
  return out;
}
union U8 { bf16x8 v; unsigned u[4]; };

#define WIDX(k0, b, c) ((k0) * 288 + 9 * (b) + (c))

// ---------------------------------------------------------------------------
// MFMA inner tile (shared by both gram paths). lds = 2 x [64][64] bf16.
// ---------------------------------------------------------------------------
__device__ __forceinline__ void gram_mfma_step(
    void* ldsraw, int tid, f32x4 (&acc)[2][2]) {
  __hip_bfloat16 (*lds)[64][64] = (__hip_bfloat16 (*)[64][64])ldsraw;
  const int lane = tid & 63;
  const int wave = tid >> 6;
  const int wm = wave >> 1, wn = wave & 1;
  #pragma unroll
  for (int ks = 0; ks < 2; ++ks) {
    bf16x8 afr[2], bfr[2];
    #pragma unroll
    for (int m = 0; m < 2; ++m) {
      int row = wm * 32 + m * 16 + (lane & 15);
      int cidx = ks * 4 + (lane >> 4);
      int cc  = cidx ^ (row & 7);
      afr[m] = *(const bf16x8*)(&lds[0][row][cc * 8]);
    }
    #pragma unroll
    for (int n = 0; n < 2; ++n) {
      int row = wn * 32 + n * 16 + (lane & 15);
      int cidx = ks * 4 + (lane >> 4);
      int cc  = cidx ^ (row & 7);
      bfr[n] = *(const bf16x8*)(&lds[1][row][cc * 8]);
    }
    #pragma unroll
    for (int m = 0; m < 2; ++m)
      #pragma unroll
      for (int n = 0; n < 2; ++n)
        acc[m][n] = __builtin_amdgcn_mfma_f32_16x16x32_bf16(
            afr[m], bfr[n], acc[m][n], 0, 0, 0);
  }
}

__device__ __forceinline__ void gram_writeback(
    float* __restrict__ C, int i0, int j0, int tid, f32x4 (&acc)[2][2]) {
  const int lane = tid & 63;
  const int wave = tid >> 6;
  const int wm = wave >> 1, wn = wave & 1;
  #pragma unroll
  for (int m = 0; m < 2; ++m)
    #pragma unroll
    for (int n = 0; n < 2; ++n)
      #pragma unroll
      for (int r = 0; r < 4; ++r) {
        int row = i0 + wm * 32 + m * 16 + (lane >> 4) * 4 + r;
        int col = j0 + wn * 32 + n * 16 + (lane & 15);
        C[(size_t)row * B_SZ + col] = acc[m][n][r];
      }
}

// ---------------------------------------------------------------------------
// psd gram body (bf16 input, global_load_lds staging)
// ---------------------------------------------------------------------------
template<int K, int LDA>
__device__ __forceinline__ void gram_body(
    const __hip_bfloat16* __restrict__ A, float* __restrict__ C,
    int i0, int j0, int tid, void* ldsraw) {
  __hip_bfloat16 (*lds)[64][64] = (__hip_bfloat16 (*)[64][64])ldsraw;
  f32x4 acc[2][2] = {};
  for (int k0 = 0; k0 < K; k0 += 64) {
    #pragma unroll
    for (int r = 0; r < 2; ++r) {
      int e   = tid + 256 * r;
      int row = e >> 3;
      int cb  = e & 7;
      int scb = cb ^ (row & 7);
      const __hip_bfloat16* srcA = A + (size_t)(i0 + row) * LDA + k0 + scb * 8;
      const __hip_bfloat16* srcB = A + (size_t)(j0 + row) * LDA + k0 + scb * 8;
      __builtin_amdgcn_global_load_lds(
          (const __attribute__((address_space(1))) void*)srcA,
          (__attribute__((address_space(3))) void*)(&lds[0][0][0] + e * 8),
          16, 0, 0);
      __builtin_amdgcn_global_load_lds(
          (const __attribute__((address_space(1))) void*)srcB,
          (__attribute__((address_space(3))) void*)(&lds[1][0][0] + e * 8),
          16, 0, 0);
    }
    __syncthreads();
    gram_mfma_step(ldsraw, tid, acc);
    __syncthreads();
  }
  gram_writeback(C, i0, j0, tid, acc);
}

// ---------------------------------------------------------------------------
// feature gram with INLINE normalization (f32 features input, K=256)
// ---------------------------------------------------------------------------
__device__ __forceinline__ void featgram_body(
    const float* __restrict__ feat, float* __restrict__ S,
    int i0, int j0, int tid, void* ldsraw) {
  __hip_bfloat16 (*lds)[64][64] = (__hip_bfloat16 (*)[64][64])ldsraw;
  float* norm_inv = (float*)((char*)ldsraw + 2 * 64 * 64 * 2);  // after 16 KB

  // row norms: 2 threads per row; rows 0..63 = i-panel, 64..127 = j-panel
  {
    const int r = tid >> 1, h = tid & 1;
    const int grow = (r < 64) ? (i0 + r) : (j0 + r - 64);
    const float4* p = (const float4*)(feat + (size_t)grow * 256 + h * 128);
    float s = 0.f;
    #pragma unroll 8
    for (int q = 0; q < 32; ++q) {
      float4 v = p[q];
      s += v.x * v.x + v.y * v.y + v.z * v.z + v.w * v.w;
    }
    s += __shfl_xor(s, 1);
    if (h == 0) norm_inv[r] = 1.0f / fmaxf(sqrtf(s), 1e-12f);
  }
  __syncthreads();

  f32x4 acc[2][2] = {};
  for (int k0 = 0; k0 < 256; k0 += 64) {
    #pragma unroll
    for (int r = 0; r < 2; ++r) {
      int e   = tid + 256 * r;
      int row = e >> 3;
      int cb  = e & 7;
      int scb = cb ^ (row & 7);
      {
        const float* src = feat + (size_t)(i0 + row) * 256 + k0 + scb * 8;
        float ni = norm_inv[row];
        U8 pk;
        #pragma unroll
        for (int q = 0; q < 4; ++q)
          pk.u[q] = cvtpk(src[2*q] * ni, src[2*q+1] * ni);
        *(bf16x8*)(&lds[0][0][0] + e * 8) = pk.v;
      }
      {
        const float* src = feat + (size_t)(j0 + row) * 256 + k0 + scb * 8;
        float ni = norm_inv[64 + row];
        U8 pk;
        #pragma unroll
        for (int q = 0; q < 4; ++q)
          pk.u[q] = cvtpk(src[2*q] * ni, src[2*q+1] * ni);
        *(bf16x8*)(&lds[1][0][0] + e * 8) = pk.v;
      }
    }
    __syncthreads();
    gram_mfma_step(ldsraw, tid, acc);
    __syncthreads();
  }
  gram_writeback(S, i0, j0, tid, acc);
}

// ---------------------------------------------------------------------------
// Kernel 2 (merged): blocks 0..1023 = traj stats; 1024..1279 = feature gram.
// ---------------------------------------------------------------------------
__global__ __launch_bounds__(256) void traj_featgram_kernel(
    const float* __restrict__ trajf,
    __hip_bfloat16* __restrict__ psd,
    float2* __restrict__ vmean,
    float2* __restrict__ wind,
    const float* __restrict__ features,
    float* __restrict__ S) {
  __shared__ __align__(16) unsigned z2w[9216];   // 36 KB (gram aliases 16.5 KB)
  __shared__ float rsum[2][4];
  __shared__ float phb[4];

  const int tid = threadIdx.x;

  if (blockIdx.x >= B_SZ) {
    const int e = blockIdx.x - B_SZ;       // 0..255
    featgram_body(features, S, (e >> 4) * 64, (e & 15) * 64, tid, (void*)z2w);
    return;
  }

  const int w   = tid >> 6;
  const int l   = tid & 63;
  const int g   = l >> 4;
  const int lc  = l & 15;
  const float* rowf = trajf + (size_t)blockIdx.x * T_LEN * 4;

  if (tid == 0) {
    phb[0] = rowf[0]; phb[1] = rowf[2];
    phb[2] = rowf[(size_t)4 * (T_LEN - 1)];
    phb[3] = rowf[(size_t)4 * (T_LEN - 1) + 2];
  }

  // ---- A fragments: DFT32 matrix W^(mk), lane holds m = mt*16+lc, k = g*8+j
  bf16x8 Ac[2], As[2], Asn[2];
  #pragma unroll
  for (int mt = 0; mt < 2; ++mt) {
    const int m = mt * 16 + lc;
    #pragma unroll
    for (int j = 0; j < 8; ++j) {
      const int idx = (m * (g * 8 + j)) & 31;
      unsigned short uc = bfb(W32C[idx]);
      unsigned short us = bfb(W32S[idx]);
      Ac[mt][j]  = (short)uc;
      As[mt][j]  = (short)us;
      Asn[mt][j] = (short)(us ^ 0x8000);
    }
  }

  float vs0 = 0.f, vs1 = 0.f;
  const f32x4 az = {0.f, 0.f, 0.f, 0.f};

  // ================= stage 1: DFT32 over a =================================
  #pragma unroll
  for (int nt = 0; nt < 4; ++nt) {
    const int n = w * 64 + nt * 16 + lc;
    float yr[8], yw[8];
    #pragma unroll
    for (int j = 0; j < 8; ++j) {
      const size_t t = (size_t)(g * 8 + j) * 256 + n;
      yr[j] = rowf[4 * t + 1];
      yw[j] = rowf[4 * t + 3];
    }
    #pragma unroll
    for (int j = 0; j < 8; ++j) { vs0 += yr[j]; vs1 += yw[j]; }
    float s0, c0;
    __sincosf(2.0f * PI_F * ((float)n / 8192.0f + (float)g * 0.25f), &s0, &c0);
    U8 xrb, xib;
    #pragma unroll
    for (int j2 = 0; j2 < 4; ++j2) {
      float w0 = 0.5f - 0.5f * (c0 * W32C[2*j2]   + s0 * W32S[2*j2]);
      float w1 = 0.5f - 0.5f * (c0 * W32C[2*j2+1] + s0 * W32S[2*j2+1]);
      xrb.u[j2] = cvtpk(yr[2*j2] * w0, yr[2*j2+1] * w1);
      xib.u[j2] = cvtpk(yw[2*j2] * w0, yw[2*j2+1] * w1);
    }
    const int bw = 9 * (n >> 3) + (n & 7);
    float ss, cs;
    __sincosf(-2.0f * PI_F * (float)n / 8192.0f, &ss, &cs);
    #pragma unroll
    for (int mt = 0; mt < 2; ++mt) {
      f32x4 ar = __builtin_amdgcn_mfma_f32_16x16x32_bf16(Asn[mt], xib.v, az, 0, 0, 0);
      ar = __builtin_amdgcn_mfma_f32_16x16x32_bf16(Ac[mt], xrb.v, ar, 0, 0, 0);
      f32x4 ai = __builtin_amdgcn_mfma_f32_16x16x32_bf16(Ac[mt], xib.v, az, 0, 0, 0);
      ai = __builtin_amdgcn_mfma_f32_16x16x32_bf16(As[mt], xrb.v, ai, 0, 0, 0);
      float sb, cb;
      __sincosf(-2.0f * PI_F * (float)n * (float)(mt * 16 + g * 4) / 8192.0f, &sb, &cb);
      #pragma unroll
      for (int r = 0; r < 4; ++r) {
        float xr_ = ar[r] * cb - ai[r] * sb;
        float xi_ = ar[r] * sb + ai[r] * cb;
        const int k0 = mt * 16 + g * 4 + r;
        z2w[k0 * 288 + bw] = cvtpk(xr_, xi_);
        float nc = cb * cs - sb * ss; sb = cb * ss + sb * cs; cb = nc;
      }
    }
  }
  __syncthreads();

  // ================= stage 2: DFT32 over b =================================
  unsigned x2_0[2][4], x2_1[2][4], x2_2[2][4], x2_3[2][4];
  #pragma unroll
  for (int nt = 0; nt < 4; ++nt) {
    const int n2 = w * 64 + nt * 16 + lc;
    const int k0 = n2 >> 3, cc = n2 & 7;
    U8 xrb, xib;
    #pragma unroll
    for (int j2 = 0; j2 < 4; ++j2) {
      unsigned p0 = z2w[WIDX(k0, g * 8 + 2*j2,     cc)];
      unsigned p1 = z2w[WIDX(k0, g * 8 + 2*j2 + 1, cc)];
      xrb.u[j2] = (p0 & 0xffffu) | (p1 << 16);
      xib.u[j2] = (p0 >> 16) | (p1 & 0xffff0000u);
    }
    #pragma unroll
    for (int mt = 0; mt < 2; ++mt) {
      f32x4 ar = __builtin_amdgcn_mfma_f32_16x16x32_bf16(Asn[mt], xib.v, az, 0, 0, 0);
      ar = __builtin_amdgcn_mfma_f32_16x16x32_bf16(Ac[mt], xrb.v, ar, 0, 0, 0);
      f32x4 ai = __builtin_amdgcn_mfma_f32_16x16x32_bf16(Ac[mt], xib.v, az, 0, 0, 0);
      ai = __builtin_amdgcn_mfma_f32_16x16x32_bf16(As[mt], xrb.v, ai, 0, 0, 0);
      float sb, cb, ss, cs;
      const float cf = (float)cc;
      __sincosf(-2.0f * PI_F * cf * (float)(mt * 16 + g * 4) / 256.0f, &sb, &cb);
      __sincosf(-2.0f * PI_F * cf / 256.0f, &ss, &cs);
      #pragma unroll
      for (int r = 0; r < 4; ++r) {
        float xr_ = ar[r] * cb - ai[r] * sb;
        float xi_ = ar[r] * sb + ai[r] * cb;
        unsigned pk = cvtpk(xr_, xi_);
        if (nt == 0) x2_0[mt][r] = pk;
        else if (nt == 1) x2_1[mt][r] = pk;
        else if (nt == 2) x2_2[mt][r] = pk;
        else x2_3[mt][r] = pk;
        float nc = cb * cs - sb * ss; sb = cb * ss + sb * cs; cb = nc;
      }
    }
  }
  __syncthreads();

  #pragma unroll
  for (int nt = 0; nt < 4; ++nt) {
    const int n2 = w * 64 + nt * 16 + lc;
    const int k0 = n2 >> 3, cc = n2 & 7;
    #pragma unroll
    for (int mt = 0; mt < 2; ++mt)
      #pragma unroll
      for (int r = 0; r < 4; ++r) {
        const int p = (mt * 16 + g * 4 + r) * 32 + k0;
        unsigned pk = (nt == 0) ? x2_0[mt][r] : (nt == 1) ? x2_1[mt][r]
                    : (nt == 2) ? x2_2[mt][r] : x2_3[mt][r];
        z2w[(p << 3) + (cc ^ ((p >> 2) & 7))] = pk;
      }
  }
  __syncthreads();

  // ================= stage 3: DFT8 over c; k2 in {0,7} =====================
  float z0r[4], z0i[4], z7r[4], z7i[4];
  #pragma unroll
  for (int q = 0; q < 4; ++q) {
    const int p = q * 256 + tid;
    float s0r = 0.f, s0i = 0.f, s7r = 0.f, s7i = 0.f;
    #pragma unroll
    for (int c2 = 0; c2 < 8; ++c2) {
      unsigned pw = z2w[(p << 3) + (c2 ^ ((p >> 2) & 7))];
      float vr = bff((unsigned short)(pw & 0xffff));
      float vi = bff((unsigned short)(pw >> 16));
      s0r += vr; s0i += vi;
      s7r += vr * E8C[c2] - vi * E8S[c2];
      s7i += vr * E8S[c2] + vi * E8C[c2];
    }
    z0r[q] = s0r; z0i[q] = s0i; z7r[q] = s7r; z7i[q] = s7i;
  }
  __syncthreads();
  float2* zf = (float2*)z2w;
  #pragma unroll
  for (int q = 0; q < 4; ++q) {
    const int p = q * 256 + tid;
    zf[p]        = make_float2(z0r[q], z0i[q]);
    zf[1024 + p] = make_float2(z7r[q], z7i[q]);
  }
  __syncthreads();

  // ---- unpack packed real FFTs -> psd (bf16), zero-pad to PSD_LDA
  for (int k = tid; k < PSD_LDA / 2; k += 256) {
    if (k < NBINS) {
      float2 Zk = zf[k];
      float2 Zn = (k == 0) ? zf[0] : zf[2048 - k];
      float fxr = 0.5f * (Zk.x + Zn.x);
      float fxi = 0.5f * (Zk.y - Zn.y);
      float fyr = 0.5f * (Zk.y + Zn.y);
      float fyi = 0.5f * (Zn.x - Zk.x);
      psd[(size_t)blockIdx.x * PSD_LDA + 2*k]     = __float2bfloat16(fxr*fxr + fxi*fxi);
      psd[(size_t)blockIdx.x * PSD_LDA + 2*k + 1] = __float2bfloat16(fyr*fyr + fyi*fyi);
    } else {
      psd[(size_t)blockIdx.x * PSD_LDA + 2*k]     = __float2bfloat16(0.0f);
      psd[(size_t)blockIdx.x * PSD_LDA + 2*k + 1] = __float2bfloat16(0.0f);
    }
  }

  // ---- v_mean and winding
  #pragma unroll
  for (int o = 32; o; o >>= 1) {
    vs0 += __shfl_down(vs0, o);
    vs1 += __shfl_down(vs1, o);
  }
  if ((tid & 63) == 0) { rsum[0][tid >> 6] = vs0; rsum[1][tid >> 6] = vs1; }
  __syncthreads();
  if (tid == 0) {
    float s0 = rsum[0][0] + rsum[0][1] + rsum[0][2] + rsum[0][3];
    float s1v = rsum[1][0] + rsum[1][1] + rsum[1][2] + rsum[1][3];
    vmean[blockIdx.x] = make_float2(s0 / (float)T_LEN, s1v / (float)T_LEN);
    const float inv2pi = 0.15915494309189535f;
    wind[blockIdx.x] = make_float2(fabsf(rintf((phb[2] - phb[0]) * inv2pi)),
                                   fabsf(rintf((phb[3] - phb[1]) * inv2pi)));
  }
}

// ---------------------------------------------------------------------------
// Kernel 3: psd gram, split-K over blockIdx.z (4 slices -> 4 blocks/CU)
// ---------------------------------------------------------------------------
template<int K, int LDA, int KOFF>
__global__ __launch_bounds__(256) void gram_mfma_kernel(
    const __hip_bfloat16* __restrict__ A, float* __restrict__ C) {
  __shared__ __align__(16) __hip_bfloat16 lds[2][64][64];  // 16 KB
  gram_body<K, LDA>(A + (size_t)blockIdx.z * KOFF,
                    C + (size_t)blockIdx.z * B_SZ * B_SZ,
                    blockIdx.y * 64, blockIdx.x * 64, threadIdx.x, (void*)lds);
}

// ---------------------------------------------------------------------------
// Kernel 4: per-row loss. G = sum of 4 split-K slices.
// ---------------------------------------------------------------------------
__global__ __launch_bounds__(256) void loss_rows_kernel(
    const float* __restrict__ S,
    const float* __restrict__ G,      // slice 0; slices at G + s*B*B
    const float* __restrict__ labels,
    const float* __restrict__ scales,
    const float2* __restrict__ vmean,
    const float2* __restrict__ wind,
    float* __restrict__ row_loss) {
  const int i = blockIdx.x;
  const int tid = threadIdx.x;
  const size_t BB = (size_t)B_SZ * B_SZ;
  const float inv_scale = 1.0f / scales[0];
  const float l0 = labels[i*3+0], l1 = labels[i*3+1], l2 = labels[i*3+2];
  const float2 vmi = vmean[i];
  const float2 wi  = wind[i];
  const float n2i = G[(size_t)i * B_SZ + i] + G[BB + (size_t)i * B_SZ + i]
                  + G[2*BB + (size_t)i * B_SZ + i] + G[3*BB + (size_t)i * B_SZ + i];
  const float normi = sqrtf(n2i);

  float posw = 0.f, den = 0.f;
  for (int j = tid; j < B_SZ; j += 256) {
    if (j == i) continue;
    float e = __expf(S[(size_t)i * B_SZ + j] * 10.0f);
    den += e;

    float d0 = (labels[j*3+0] - l0) * inv_scale;
    float d1 = (labels[j*3+1] - l1) * inv_scale;
    float d2v = (labels[j*3+2] - l2) * inv_scale;
    float pd = sqrtf(d0*d0 + d1*d1 + d2v*d2v);
    float pw = __expf(-pd * 10.0f);

    float2 vmj = vmean[j];
    float dvx = vmi.x - vmj.x, dvy = vmi.y - vmj.y;
    float v_sim = __expf(-sqrtf(dvx*dvx + dvy*dvy) * 2.0f);

    float n2j = G[(size_t)j * B_SZ + j] + G[BB + (size_t)j * B_SZ + j]
              + G[2*BB + (size_t)j * B_SZ + j] + G[3*BB + (size_t)j * B_SZ + j];
    float gg  = G[(size_t)i * B_SZ + j] + G[BB + (size_t)i * B_SZ + j]
              + G[2*BB + (size_t)i * B_SZ + j] + G[3*BB + (size_t)i * B_SZ + j];
    float dd  = fmaxf(n2i + n2j - 2.0f * gg, 0.0f);
    float psd_dist = sqrtf(dd);
    float norma = (i < j) ? normi : sqrtf(n2j);
    float psd_sim = __expf(-psd_dist / (norma + 1e-8f));

    float2 wj = wind[j];
    float w_sim = (wi.x == wj.x && wi.y == wj.y) ? 1.0f : 0.0f;

    float kin = 0.4f * v_sim + 0.4f * psd_sim + 0.2f * w_sim;
    posw += e * pw * kin;
  }

  #pragma unroll
  for (int o = 32; o; o >>= 1) {
    posw += __shfl_down(posw, o);
    den  += __shfl_down(den, o);
  }
  __shared__ float bp[4], bd[4];
  if ((tid & 63) == 0) { bp[tid >> 6] = posw; bd[tid >> 6] = den; }
  __syncthreads();
  if (tid == 0) {
    float P = bp[0] + bp[1] + bp[2] + bp[3];
    float D = bd[0] + bd[1] + bd[2] + bd[3];
    row_loss[i] = -logf((P + 1e-8f) / (D + 1e-8f));
  }
}

// ---------------------------------------------------------------------------
// Kernel 5: mean of row losses -> scalar
// ---------------------------------------------------------------------------
__global__ __launch_bounds__(256) void reduce_mean_kernel(
    const float* __restrict__ row_loss, float* __restrict__ out) {
  int tid = threadIdx.x;
  float s = 0.f;
  for (int i = tid; i < B_SZ; i += 256) s += row_loss[i];
  #pragma unroll
  for (int o = 32; o; o >>= 1) s += __shfl_down(s, o);
  __shared__ float buf[4];
  if ((tid & 63) == 0) buf[tid >> 6] = s;
  __syncthreads();
  if (tid == 0) out[0] = (buf[0] + buf[1] + buf[2] + buf[3]) / (float)B_SZ;
}

// ---------------------------------------------------------------------------
extern "C" void kernel_launch(void* const* d_in, const int* in_sizes, int n_in,
                              void* d_out, int out_size, void* d_ws, size_t ws_size,
                              hipStream_t stream) {
  const float* features = (const float*)d_in[0];
  const float* labels   = (const float*)d_in[1];
  const float* traj     = (const float*)d_in[2];
  const float* scales   = (const float*)d_in[3];

  char* ws = (char*)d_ws;
  __hip_bfloat16* psd = (__hip_bfloat16*)ws;                       // 3.5 MB
  float* G = (float*)(ws + (size_t)B_SZ * PSD_LDA * 2);            // 4 x 4 MB slices
  float* S = G + 4 * (size_t)B_SZ * B_SZ;                          // 4 MB
  float2* vmean = (float2*)(S + (size_t)B_SZ * B_SZ);
  float2* wind  = vmean + B_SZ;
  float* row_loss = (float*)(wind + B_SZ);

  // merged: 1024 traj blocks + 256 feature-gram blocks (inline normalize)
  traj_featgram_kernel<<<B_SZ + 256, 256, 0, stream>>>(
      traj, psd, vmean, wind, features, S);

  // psd gram split-K: 1792 = 4 x 448; one dispatch, 1024 blocks (4/CU)
  dim3 gridPsd(16, 16, 4);
  gram_mfma_kernel<448, PSD_LDA, 448><<<gridPsd, 256, 0, stream>>>(psd, G);

  loss_rows_kernel<<<B_SZ, 256, 0, stream>>>(S, G, labels, scales, vmean, wind, row_loss);
  reduce_mean_kernel<<<1, 256, 0, stream>>>(row_loss, (float*)d_out);
}

// Round 15
// 62.586 us; speedup vs baseline: 1.0884x; 1.0884x over previous
//
#include <hip/hip_runtime.h>
#include <hip/hip_bf16.h>

#define B_SZ 1024
#define T_LEN 8192
#define NBINS 819            // T//10
#define PSD_LDA 1664         // padded bf16 row stride (zero-padded 1638..1663)
#define PI_F 3.14159265358979323846f

typedef __attribute__((ext_vector_type(8))) short bf16x8;
typedef __attribute__((ext_vector_type(4))) float f32x4;

// ---- tables ---------------------------------------------------------------
__device__ constexpr float W32C[32] = {   // cos(2*pi*m/32)
  1.0f, 0.980785280f, 0.923879533f, 0.831469612f, 0.707106781f, 0.555570233f,
  0.382683432f, 0.195090322f, 0.0f, -0.195090322f, -0.382683432f, -0.555570233f,
  -0.707106781f, -0.831469612f, -0.923879533f, -0.980785280f, -1.0f,
  -0.980785280f, -0.923879533f, -0.831469612f, -0.707106781f, -0.555570233f,
  -0.382683432f, -0.195090322f, 0.0f, 0.195090322f, 0.382683432f, 0.555570233f,
  0.707106781f, 0.831469612f, 0.923879533f, 0.980785280f};
__device__ constexpr float W32S[32] = {   // -sin(2*pi*m/32)
  0.0f, -0.195090322f, -0.382683432f, -0.555570233f, -0.707106781f,
  -0.831469612f, -0.923879533f, -0.980785280f, -1.0f, -0.980785280f,
  -0.923879533f, -0.831469612f, -0.707106781f, -0.555570233f, -0.382683432f,
  -0.195090322f, 0.0f, 0.195090322f, 0.382683432f, 0.555570233f, 0.707106781f,
  0.831469612f, 0.923879533f, 0.980785280f, 1.0f, 0.980785280f, 0.923879533f,
  0.831469612f, 0.707106781f, 0.555570233f, 0.382683432f, 0.195090322f};
__device__ constexpr float E8C[8] = {  // cos(pi*c/4)
  1.0f, 0.707106781f, 0.0f, -0.707106781f, -1.0f, -0.707106781f, 0.0f, 0.707106781f};
__device__ constexpr float E8S[8] = {  // sin(pi*c/4)
  0.0f, 0.707106781f, 1.0f, 0.707106781f, 0.0f, -0.707106781f, -1.0f, -0.707106781f};

__device__ __forceinline__ unsigned short bfb(float x) {
  __hip_bfloat16 h = __float2bfloat16(x);
  return *(unsigned short*)&h;
}
__device__ __forceinline__ float bff(unsigned short u) {
  union { unsigned u; float f; } v; v.u = ((unsigned)u) << 16; return v.f;
}
__device__ __forceinline__ unsigned cvtpk(float r, float i) {
  unsigned out;
  asm("v_cvt_pk_bf16_f32 %0, %1, %2" : "=v"(out) : "v"(r), "v"(i));
  return out;
}
union U8 { bf16x8 v; unsigned u[4]; };

#define WIDX(k0, b, c) ((k0) * 288 + 9 * (b) + (c))

// ---------------------------------------------------------------------------
// Shared gram body: C[i0:i0+64][j0:j0+64] = A(i0 rows) . A(j0 rows)^T
// ---------------------------------------------------------------------------
template<int K, int LDA>
__device__ __forceinline__ void gram_body(
    const __hip_bfloat16* __restrict__ A, float* __restrict__ C,
    int i0, int j0, int tid, void* ldsraw) {
  __hip_bfloat16 (*lds)[64][64] = (__hip_bfloat16 (*)[64][64])ldsraw;
  const int lane = tid & 63;
  const int wave = tid >> 6;
  const int wm = wave >> 1, wn = wave & 1;

  f32x4 acc[2][2] = {};

  for (int k0 = 0; k0 < K; k0 += 64) {
    #pragma unroll
    for (int r = 0; r < 2; ++r) {
      int e   = tid + 256 * r;
      int row = e >> 3;
      int cb  = e & 7;
      int scb = cb ^ (row & 7);
      const __hip_bfloat16* srcA = A + (size_t)(i0 + row) * LDA + k0 + scb * 8;
      const __hip_bfloat16* srcB = A + (size_t)(j0 + row) * LDA + k0 + scb * 8;
      __builtin_amdgcn_global_load_lds(
          (const __attribute__((address_space(1))) void*)srcA,
          (__attribute__((address_space(3))) void*)(&lds[0][0][0] + e * 8),
          16, 0, 0);
      __builtin_amdgcn_global_load_lds(
          (const __attribute__((address_space(1))) void*)srcB,
          (__attribute__((address_space(3))) void*)(&lds[1][0][0] + e * 8),
          16, 0, 0);
    }
    __syncthreads();

    #pragma unroll
    for (int ks = 0; ks < 2; ++ks) {
      bf16x8 afr[2], bfr[2];
      #pragma unroll
      for (int m = 0; m < 2; ++m) {
        int row = wm * 32 + m * 16 + (lane & 15);
        int cidx = ks * 4 + (lane >> 4);
        int cc  = cidx ^ (row & 7);
        afr[m] = *(const bf16x8*)(&lds[0][row][cc * 8]);
      }
      #pragma unroll
      for (int n = 0; n < 2; ++n) {
        int row = wn * 32 + n * 16 + (lane & 15);
        int cidx = ks * 4 + (lane >> 4);
        int cc  = cidx ^ (row & 7);
        bfr[n] = *(const bf16x8*)(&lds[1][row][cc * 8]);
      }
      #pragma unroll
      for (int m = 0; m < 2; ++m)
        #pragma unroll
        for (int n = 0; n < 2; ++n)
          acc[m][n] = __builtin_amdgcn_mfma_f32_16x16x32_bf16(
              afr[m], bfr[n], acc[m][n], 0, 0, 0);
    }
    __syncthreads();
  }

  #pragma unroll
  for (int m = 0; m < 2; ++m)
    #pragma unroll
    for (int n = 0; n < 2; ++n)
      #pragma unroll
      for (int r = 0; r < 4; ++r) {
        int row = i0 + wm * 32 + m * 16 + (lane >> 4) * 4 + r;
        int col = j0 + wn * 32 + n * 16 + (lane & 15);
        C[(size_t)row * B_SZ + col] = acc[m][n][r];
      }
}

// ---------------------------------------------------------------------------
// Kernel 1: normalize feature rows (B x 256) -> bf16
// ---------------------------------------------------------------------------
__global__ __launch_bounds__(256) void normalize_kernel(
    const float* __restrict__ f, __hip_bfloat16* __restrict__ fn) {
  int i = blockIdx.x;
  int t = threadIdx.x;
  float v = f[(size_t)i * 256 + t];
  float s = v * v;
  #pragma unroll
  for (int o = 32; o; o >>= 1) s += __shfl_down(s, o);
  __shared__ float buf[4];
  if ((t & 63) == 0) buf[t >> 6] = s;
  __syncthreads();
  float norm = sqrtf(buf[0] + buf[1] + buf[2] + buf[3]);
  norm = fmaxf(norm, 1e-12f);
  fn[(size_t)i * 256 + t] = __float2bfloat16(v / norm);
}

// ---------------------------------------------------------------------------
// Kernel 2 (merged): blocks 0..1023 = traj stats (R11 path, unchanged);
// blocks 1024..1279 = feature gram (overlaps traj's stall time).
// ---------------------------------------------------------------------------
__global__ __launch_bounds__(256) void traj_featgram_kernel(
    const float* __restrict__ trajf,
    __hip_bfloat16* __restrict__ psd,
    float2* __restrict__ vmean,
    float2* __restrict__ wind,
    const __hip_bfloat16* __restrict__ f_n,
    float* __restrict__ S) {
  __shared__ __align__(16) unsigned z2w[9216];   // 36 KB (gram aliases 16 KB)
  __shared__ float rsum[2][4];
  __shared__ float phb[4];

  const int tid = threadIdx.x;

  if (blockIdx.x >= B_SZ) {
    const int e  = blockIdx.x - B_SZ;       // 0..255
    gram_body<256, 256>(f_n, S, (e >> 4) * 64, (e & 15) * 64, tid, (void*)z2w);
    return;
  }

  const int w   = tid >> 6;
  const int l   = tid & 63;
  const int g   = l >> 4;
  const int lc  = l & 15;
  const float* rowf = trajf + (size_t)blockIdx.x * T_LEN * 4;

  if (tid == 0) {
    phb[0] = rowf[0]; phb[1] = rowf[2];
    phb[2] = rowf[(size_t)4 * (T_LEN - 1)];
    phb[3] = rowf[(size_t)4 * (T_LEN - 1) + 2];
  }

  // ---- A fragments: DFT32 matrix W^(mk), lane holds m = mt*16+lc, k = g*8+j
  bf16x8 Ac[2], As[2], Asn[2];
  #pragma unroll
  for (int mt = 0; mt < 2; ++mt) {
    const int m = mt * 16 + lc;
    #pragma unroll
    for (int j = 0; j < 8; ++j) {
      const int idx = (m * (g * 8 + j)) & 31;
      unsigned short uc = bfb(W32C[idx]);
      unsigned short us = bfb(W32S[idx]);
      Ac[mt][j]  = (short)uc;
      As[mt][j]  = (short)us;
      Asn[mt][j] = (short)(us ^ 0x8000);
    }
  }

  float vs0 = 0.f, vs1 = 0.f;
  const f32x4 az = {0.f, 0.f, 0.f, 0.f};

  // ================= stage 1: DFT32 over a =================================
  #pragma unroll
  for (int nt = 0; nt < 4; ++nt) {
    const int n = w * 64 + nt * 16 + lc;
    float yr[8], yw[8];
    #pragma unroll
    for (int j = 0; j < 8; ++j) {
      const size_t t = (size_t)(g * 8 + j) * 256 + n;
      yr[j] = rowf[4 * t + 1];
      yw[j] = rowf[4 * t + 3];
    }
    #pragma unroll
    for (int j = 0; j < 8; ++j) { vs0 += yr[j]; vs1 += yw[j]; }
    float s0, c0;
    __sincosf(2.0f * PI_F * ((float)n / 8192.0f + (float)g * 0.25f), &s0, &c0);
    U8 xrb, xib;
    #pragma unroll
    for (int j2 = 0; j2 < 4; ++j2) {
      float w0 = 0.5f - 0.5f * (c0 * W32C[2*j2]   + s0 * W32S[2*j2]);
      float w1 = 0.5f - 0.5f * (c0 * W32C[2*j2+1] + s0 * W32S[2*j2+1]);
      xrb.u[j2] = cvtpk(yr[2*j2] * w0, yr[2*j2+1] * w1);
      xib.u[j2] = cvtpk(yw[2*j2] * w0, yw[2*j2+1] * w1);
    }
    const int bw = 9 * (n >> 3) + (n & 7);
    float ss, cs;
    __sincosf(-2.0f * PI_F * (float)n / 8192.0f, &ss, &cs);
    #pragma unroll
    for (int mt = 0; mt < 2; ++mt) {
      f32x4 ar = __builtin_amdgcn_mfma_f32_16x16x32_bf16(Asn[mt], xib.v, az, 0, 0, 0);
      ar = __builtin_amdgcn_mfma_f32_16x16x32_bf16(Ac[mt], xrb.v, ar, 0, 0, 0);
      f32x4 ai = __builtin_amdgcn_mfma_f32_16x16x32_bf16(Ac[mt], xib.v, az, 0, 0, 0);
      ai = __builtin_amdgcn_mfma_f32_16x16x32_bf16(As[mt], xrb.v, ai, 0, 0, 0);
      float sb, cb;
      __sincosf(-2.0f * PI_F * (float)n * (float)(mt * 16 + g * 4) / 8192.0f, &sb, &cb);
      #pragma unroll
      for (int r = 0; r < 4; ++r) {
        float xr_ = ar[r] * cb - ai[r] * sb;
        float xi_ = ar[r] * sb + ai[r] * cb;
        const int k0 = mt * 16 + g * 4 + r;
        z2w[k0 * 288 + bw] = cvtpk(xr_, xi_);
        float nc = cb * cs - sb * ss; sb = cb * ss + sb * cs; cb = nc;
      }
    }
  }
  __syncthreads();

  // ================= stage 2: DFT32 over b =================================
  unsigned x2_0[2][4], x2_1[2][4], x2_2[2][4], x2_3[2][4];
  #pragma unroll
  for (int nt = 0; nt < 4; ++nt) {
    const int n2 = w * 64 + nt * 16 + lc;
    const int k0 = n2 >> 3, cc = n2 & 7;
    U8 xrb, xib;
    #pragma unroll
    for (int j2 = 0; j2 < 4; ++j2) {
      unsigned p0 = z2w[WIDX(k0, g * 8 + 2*j2,     cc)];
      unsigned p1 = z2w[WIDX(k0, g * 8 + 2*j2 + 1, cc)];
      xrb.u[j2] = (p0 & 0xffffu) | (p1 << 16);
      xib.u[j2] = (p0 >> 16) | (p1 & 0xffff0000u);
    }
    #pragma unroll
    for (int mt = 0; mt < 2; ++mt) {
      f32x4 ar = __builtin_amdgcn_mfma_f32_16x16x32_bf16(Asn[mt], xib.v, az, 0, 0, 0);
      ar = __builtin_amdgcn_mfma_f32_16x16x32_bf16(Ac[mt], xrb.v, ar, 0, 0, 0);
      f32x4 ai = __builtin_amdgcn_mfma_f32_16x16x32_bf16(Ac[mt], xib.v, az, 0, 0, 0);
      ai = __builtin_amdgcn_mfma_f32_16x16x32_bf16(As[mt], xrb.v, ai, 0, 0, 0);
      float sb, cb, ss, cs;
      const float cf = (float)cc;
      __sincosf(-2.0f * PI_F * cf * (float)(mt * 16 + g * 4) / 256.0f, &sb, &cb);
      __sincosf(-2.0f * PI_F * cf / 256.0f, &ss, &cs);
      #pragma unroll
      for (int r = 0; r < 4; ++r) {
        float xr_ = ar[r] * cb - ai[r] * sb;
        float xi_ = ar[r] * sb + ai[r] * cb;
        unsigned pk = cvtpk(xr_, xi_);
        if (nt == 0) x2_0[mt][r] = pk;
        else if (nt == 1) x2_1[mt][r] = pk;
        else if (nt == 2) x2_2[mt][r] = pk;
        else x2_3[mt][r] = pk;
        float nc = cb * cs - sb * ss; sb = cb * ss + sb * cs; cb = nc;
      }
    }
  }
  __syncthreads();

  #pragma unroll
  for (int nt = 0; nt < 4; ++nt) {
    const int n2 = w * 64 + nt * 16 + lc;
    const int k0 = n2 >> 3, cc = n2 & 7;
    #pragma unroll
    for (int mt = 0; mt < 2; ++mt)
      #pragma unroll
      for (int r = 0; r < 4; ++r) {
        const int p = (mt * 16 + g * 4 + r) * 32 + k0;
        unsigned pk = (nt == 0) ? x2_0[mt][r] : (nt == 1) ? x2_1[mt][r]
                    : (nt == 2) ? x2_2[mt][r] : x2_3[mt][r];
        z2w[(p << 3) + (cc ^ ((p >> 2) & 7))] = pk;
      }
  }
  __syncthreads();

  // ================= stage 3: DFT8 over c; k2 in {0,7} =====================
  float z0r[4], z0i[4], z7r[4], z7i[4];
  #pragma unroll
  for (int q = 0; q < 4; ++q) {
    const int p = q * 256 + tid;
    float s0r = 0.f, s0i = 0.f, s7r = 0.f, s7i = 0.f;
    #pragma unroll
    for (int c2 = 0; c2 < 8; ++c2) {
      unsigned pw = z2w[(p << 3) + (c2 ^ ((p >> 2) & 7))];
      float vr = bff((unsigned short)(pw & 0xffff));
      float vi = bff((unsigned short)(pw >> 16));
      s0r += vr; s0i += vi;
      s7r += vr * E8C[c2] - vi * E8S[c2];
      s7i += vr * E8S[c2] + vi * E8C[c2];
    }
    z0r[q] = s0r; z0i[q] = s0i; z7r[q] = s7r; z7i[q] = s7i;
  }
  __syncthreads();
  float2* zf = (float2*)z2w;
  #pragma unroll
  for (int q = 0; q < 4; ++q) {
    const int p = q * 256 + tid;
    zf[p]        = make_float2(z0r[q], z0i[q]);
    zf[1024 + p] = make_float2(z7r[q], z7i[q]);
  }
  __syncthreads();

  // ---- unpack packed real FFTs -> psd (bf16), zero-pad to PSD_LDA
  for (int k = tid; k < PSD_LDA / 2; k += 256) {
    if (k < NBINS) {
      float2 Zk = zf[k];
      float2 Zn = (k == 0) ? zf[0] : zf[2048 - k];
      float fxr = 0.5f * (Zk.x + Zn.x);
      float fxi = 0.5f * (Zk.y - Zn.y);
      float fyr = 0.5f * (Zk.y + Zn.y);
      float fyi = 0.5f * (Zn.x - Zk.x);
      psd[(size_t)blockIdx.x * PSD_LDA + 2*k]     = __float2bfloat16(fxr*fxr + fxi*fxi);
      psd[(size_t)blockIdx.x * PSD_LDA + 2*k + 1] = __float2bfloat16(fyr*fyr + fyi*fyi);
    } else {
      psd[(size_t)blockIdx.x * PSD_LDA + 2*k]     = __float2bfloat16(0.0f);
      psd[(size_t)blockIdx.x * PSD_LDA + 2*k + 1] = __float2bfloat16(0.0f);
    }
  }

  // ---- v_mean and winding
  #pragma unroll
  for (int o = 32; o; o >>= 1) {
    vs0 += __shfl_down(vs0, o);
    vs1 += __shfl_down(vs1, o);
  }
  if ((tid & 63) == 0) { rsum[0][tid >> 6] = vs0; rsum[1][tid >> 6] = vs1; }
  __syncthreads();
  if (tid == 0) {
    float s0 = rsum[0][0] + rsum[0][1] + rsum[0][2] + rsum[0][3];
    float s1v = rsum[1][0] + rsum[1][1] + rsum[1][2] + rsum[1][3];
    vmean[blockIdx.x] = make_float2(s0 / (float)T_LEN, s1v / (float)T_LEN);
    const float inv2pi = 0.15915494309189535f;
    wind[blockIdx.x] = make_float2(fabsf(rintf((phb[2] - phb[0]) * inv2pi)),
                                   fabsf(rintf((phb[3] - phb[1]) * inv2pi)));
  }
}

// ---------------------------------------------------------------------------
// Kernel 3: psd gram, split-K over blockIdx.z (2 slices -> 2 blocks/CU)
// ---------------------------------------------------------------------------
template<int K, int LDA, int KOFF>
__global__ __launch_bounds__(256) void gram_mfma_kernel(
    const __hip_bfloat16* __restrict__ A, float* __restrict__ C) {
  __shared__ __align__(16) __hip_bfloat16 lds[2][64][64];  // 16 KB
  gram_body<K, LDA>(A + (size_t)blockIdx.z * KOFF,
                    C + (size_t)blockIdx.z * B_SZ * B_SZ,
                    blockIdx.y * 64, blockIdx.x * 64, threadIdx.x, (void*)lds);
}

// ---------------------------------------------------------------------------
// Kernel 4: per-row loss. One block per row i. G = G1 + G2 (split-K halves).
// ---------------------------------------------------------------------------
__global__ __launch_bounds__(256) void loss_rows_kernel(
    const float* __restrict__ S,
    const float* __restrict__ G,      // half 1; half 2 at G + B*B
    const float* __restrict__ labels,
    const float* __restrict__ scales,
    const float2* __restrict__ vmean,
    const float2* __restrict__ wind,
    float* __restrict__ row_loss) {
  const int i = blockIdx.x;
  const int tid = threadIdx.x;
  const float* G2 = G + (size_t)B_SZ * B_SZ;
  const float inv_scale = 1.0f / scales[0];
  const float l0 = labels[i*3+0], l1 = labels[i*3+1], l2 = labels[i*3+2];
  const float2 vmi = vmean[i];
  const float2 wi  = wind[i];
  const float n2i  = G[(size_t)i * B_SZ + i] + G2[(size_t)i * B_SZ + i];
  const float normi = sqrtf(n2i);

  float posw = 0.f, den = 0.f;
  for (int j = tid; j < B_SZ; j += 256) {
    if (j == i) continue;
    float e = __expf(S[(size_t)i * B_SZ + j] * 10.0f);
    den += e;

    float d0 = (labels[j*3+0] - l0) * inv_scale;
    float d1 = (labels[j*3+1] - l1) * inv_scale;
    float d2v = (labels[j*3+2] - l2) * inv_scale;
    float pd = sqrtf(d0*d0 + d1*d1 + d2v*d2v);
    float pw = __expf(-pd * 10.0f);

    float2 vmj = vmean[j];
    float dvx = vmi.x - vmj.x, dvy = vmi.y - vmj.y;
    float v_sim = __expf(-sqrtf(dvx*dvx + dvy*dvy) * 2.0f);

    float n2j = G[(size_t)j * B_SZ + j] + G2[(size_t)j * B_SZ + j];
    float gg  = G[(size_t)i * B_SZ + j] + G2[(size_t)i * B_SZ + j];
    float dd  = fmaxf(n2i + n2j - 2.0f * gg, 0.0f);
    float psd_dist = sqrtf(dd);
    float norma = (i < j) ? normi : sqrtf(n2j);
    float psd_sim = __expf(-psd_dist / (norma + 1e-8f));

    float2 wj = wind[j];
    float w_sim = (wi.x == wj.x && wi.y == wj.y) ? 1.0f : 0.0f;

    float kin = 0.4f * v_sim + 0.4f * psd_sim + 0.2f * w_sim;
    posw += e * pw * kin;
  }

  #pragma unroll
  for (int o = 32; o; o >>= 1) {
    posw += __shfl_down(posw, o);
    den  += __shfl_down(den, o);
  }
  __shared__ float bp[4], bd[4];
  if ((tid & 63) == 0) { bp[tid >> 6] = posw; bd[tid >> 6] = den; }
  __syncthreads();
  if (tid == 0) {
    float P = bp[0] + bp[1] + bp[2] + bp[3];
    float D = bd[0] + bd[1] + bd[2] + bd[3];
    row_loss[i] = -logf((P + 1e-8f) / (D + 1e-8f));
  }
}

// ---------------------------------------------------------------------------
// Kernel 5: mean of row losses -> scalar
// ---------------------------------------------------------------------------
__global__ __launch_bounds__(256) void reduce_mean_kernel(
    const float* __restrict__ row_loss, float* __restrict__ out) {
  int tid = threadIdx.x;
  float s = 0.f;
  for (int i = tid; i < B_SZ; i += 256) s += row_loss[i];
  #pragma unroll
  for (int o = 32; o; o >>= 1) s += __shfl_down(s, o);
  __shared__ float buf[4];
  if ((tid & 63) == 0) buf[tid >> 6] = s;
  __syncthreads();
  if (tid == 0) out[0] = (buf[0] + buf[1] + buf[2] + buf[3]) / (float)B_SZ;
}

// ---------------------------------------------------------------------------
extern "C" void kernel_launch(void* const* d_in, const int* in_sizes, int n_in,
                              void* d_out, int out_size, void* d_ws, size_t ws_size,
                              hipStream_t stream) {
  const float* features = (const float*)d_in[0];
  const float* labels   = (const float*)d_in[1];
  const float* traj     = (const float*)d_in[2];
  const float* scales   = (const float*)d_in[3];

  char* ws = (char*)d_ws;
  __hip_bfloat16* f_n = (__hip_bfloat16*)ws;                               // 0.5 MB
  __hip_bfloat16* psd = (__hip_bfloat16*)(ws + (size_t)B_SZ*256*2);        // 3.25 MB
  float* G = (float*)(ws + (size_t)B_SZ*256*2 + (size_t)B_SZ*PSD_LDA*2);   // 4 MB (half 1)
  // G2 = G + B*B (4 MB, half 2)
  float* S = G + 2 * (size_t)B_SZ * B_SZ;                                  // 4 MB
  float2* vmean = (float2*)(S + (size_t)B_SZ * B_SZ);
  float2* wind  = vmean + B_SZ;
  float* row_loss = (float*)(wind + B_SZ);

  normalize_kernel<<<B_SZ, 256, 0, stream>>>(features, f_n);
  // merged: 1024 traj blocks + 256 feature-gram blocks
  traj_featgram_kernel<<<B_SZ + 256, 256, 0, stream>>>(
      traj, psd, vmean, wind, f_n, S);

  // psd gram split-K: 1664 = 2 x 832; one dispatch, 512 blocks (2/CU)
  dim3 gridPsd(16, 16, 2);
  gram_mfma_kernel<832, PSD_LDA, 832><<<gridPsd, 256, 0, stream>>>(psd, G);

  loss_rows_kernel<<<B_SZ, 256, 0, stream>>>(S, G, labels, scales, vmean, wind, row_loss);
  reduce_mean_kernel<<<1, 256, 0, stream>>>(row_loss, (float*)d_out);
}